// Round 5
// baseline (168.831 us; speedup 1.0000x reference)
//
#include <hip/hip_runtime.h>

typedef __attribute__((ext_vector_type(8))) short bf16x8;
typedef __attribute__((ext_vector_type(4))) float f32x4;
typedef __attribute__((ext_vector_type(4))) unsigned int u32x4;
typedef __attribute__((ext_vector_type(8))) unsigned short bfu8;

#define BB 4
#define SS 2048
#define DD 512
#define HH 8
#define DKK 64
#define WWIN 16
#define MTOT (BB*SS)                 /* 8192 */
#define MKE  ((long)MTOT*DD)         /* 4,194,304 elems */
#define NKE  ((long)DD*DD)           /* 262,144 elems */

__device__ __forceinline__ unsigned short f2bf(float f) {
  unsigned int u = __float_as_uint(f);
  u += 0x7fffu + ((u >> 16) & 1u);
  return (unsigned short)(u >> 16);
}
__device__ __forceinline__ float bf2f(unsigned short s) {
  return __uint_as_float(((unsigned int)s) << 16);
}

__device__ __forceinline__ void gload_lds16(const unsigned short* g, unsigned short* l) {
  __builtin_amdgcn_global_load_lds((const __attribute__((address_space(1))) void*)g,
                                   (__attribute__((address_space(3))) void*)l, 16, 0, 0);
}

// -------- transpose+convert weights: Wt[n][k] = bf16(W[k][n]); blocks 256..261 gather biases --------
__global__ __launch_bounds__(256) void convert_w(
    const float* __restrict__ Wq, const float* __restrict__ Wk,
    const float* __restrict__ Wv, const float* __restrict__ Wo,
    const float* __restrict__ bq, const float* __restrict__ bk, const float* __restrict__ bv,
    unsigned short* __restrict__ wt, float* __restrict__ bias_all)
{
  int bx = blockIdx.x;
  if (bx >= 256) {                       // bias gather: 6 blocks x 256 = 1536
    int idx = (bx - 256) * 256 + threadIdx.x;
    bias_all[idx] = idx < DD ? bq[idx] : (idx < 2*DD ? bk[idx-DD] : bv[idx-2*DD]);
    return;
  }
  int wm = bx >> 6;
  int tile = bx & 63;
  int tr = tile >> 3, tc = tile & 7;     // 8x8 tiles of 64x64
  const float* src = wm==0 ? Wq : wm==1 ? Wk : wm==2 ? Wv : Wo;
  unsigned short* dst = wt + (long)wm*NKE;
  __shared__ float tl[64][65];
  int t = threadIdx.x;
  int cr = t >> 6;                       // 0..3
  int cc = t & 63;
  for (int p = 0; p < 16; ++p) {
    int row = p*4 + cr;
    tl[row][cc] = src[(long)(tr*64+row)*DD + tc*64 + cc];
  }
  __syncthreads();
  for (int p = 0; p < 16; ++p) {
    int orow = p*4 + cr;                 // output row = original col
    dst[(long)(tc*64 + orow)*DD + tr*64 + cc] = f2bf(tl[cc][orow]);
  }
}

// -------- row-panel MFMA GEMM: each block computes a 32-row x N(=512) panel --------
// A read from HBM exactly once (no inter-block A reuse needed). Bt slab (512x64/K-step)
// streamed from L2 via global_load_lds. 4 waves, wave w owns cols [128w,128w+128).
// acc 2x8 frags = 64 VGPR. A_FP32: reg-stage A with on-the-fly bf16 conversion.
template<int OUT_BF16, int A_FP32>
__global__ __launch_bounds__(256, 2) void gemm_rowpanel(
    const void* __restrict__ a0, const void* __restrict__ a1, const void* __restrict__ a2,
    const unsigned short* __restrict__ Btbase, long bZ,
    const float* __restrict__ biasBase, long biasZ,
    void* __restrict__ outBase, long outZ,
    int N, int K)
{
  const int z = blockIdx.z;
  const void* Av = z==0 ? a0 : z==1 ? a1 : a2;
  const unsigned short* Bt = Btbase + (long)z*bZ;
  const float* bias = biasBase + (long)z*biasZ;

  const int tid = threadIdx.x, lane = tid & 63, w = tid >> 6;
  const int c = lane & 15, g = lane >> 4;
  const int m0 = blockIdx.x * 32;

  __shared__ unsigned short lA[32*64];     // 4 KB
  __shared__ unsigned short lB[512*64];    // 64 KB

  f32x4 acc[2][8] = {};

  for (int kt = 0; kt < K; kt += 64) {
    // stage Bt 512x64 (64 KB) via global_load_lds: 16 issues/thread, L2-resident source
    for (int i = 0; i < 16; ++i) {
      int u = i*256 + tid;                 // 16B-chunk id, 0..4095
      int row = u >> 3, col = (u & 7) * 8;
      gload_lds16(Bt + (long)row*K + kt + col, &lB[i*2048 + w*512]);
    }
    // stage A 32x64: one 16B chunk per thread
    {
      int row = tid >> 3, col = (tid & 7) * 8;
      if (A_FP32) {
        const float* Afp = (const float*)Av;
        const float* src = Afp + (long)(m0 + row)*K + kt + col;
        float4 f0 = *(const float4*)src;
        float4 f1 = *(const float4*)(src + 4);
        bfu8 o;
        o[0]=f2bf(f0.x); o[1]=f2bf(f0.y); o[2]=f2bf(f0.z); o[3]=f2bf(f0.w);
        o[4]=f2bf(f1.x); o[5]=f2bf(f1.y); o[6]=f2bf(f1.z); o[7]=f2bf(f1.w);
        *(bfu8*)&lA[tid*8] = o;
      } else {
        const unsigned short* A = (const unsigned short*)Av;
        gload_lds16(A + (long)(m0 + row)*K + kt + col, &lA[w*512]);
      }
    }
    __syncthreads();
    for (int kk = 0; kk < 2; ++kk) {
      bf16x8 af[2], bfr[8];
      for (int m = 0; m < 2; ++m)
        af[m] = *reinterpret_cast<const bf16x8*>(&lA[(m*16 + c)*64 + kk*32 + g*8]);
      for (int n = 0; n < 8; ++n)
        bfr[n] = *reinterpret_cast<const bf16x8*>(&lB[(w*128 + n*16 + c)*64 + kk*32 + g*8]);
      for (int m = 0; m < 2; ++m)
        for (int n = 0; n < 8; ++n)
          acc[m][n] = __builtin_amdgcn_mfma_f32_16x16x32_bf16(af[m], bfr[n], acc[m][n], 0, 0, 0);
    }
    __syncthreads();
  }

  // epilogue: C/D layout col=lane&15, row=(lane>>4)*4+reg
  for (int m = 0; m < 2; ++m) {
    int rbase = m0 + m*16 + g*4;
    for (int n = 0; n < 8; ++n) {
      int col = w*128 + n*16 + c;
      float bv = bias[col];
      for (int r = 0; r < 4; ++r) {
        float val = acc[m][n][r] + bv;
        long idx = (long)z*outZ + (long)(rbase + r)*N + col;
        if (OUT_BF16) ((unsigned short*)outBase)[idx] = f2bf(val);
        else          ((float*)outBase)[idx] = val;
      }
    }
  }
}

// ---------------- banded local attention via MFMA ----------------
// grid: (S/128, H, B); block 256 = 4 waves; wave w owns queries [q0+32w, q0+32w+32)
// K/V window staged: rows [q0-16, q0+144) = 160 rows x 64 dk (zero-filled OOB)
#define KP 76   /* LDS row pad (elems): keeps hot ds_read <=2-way bank aliased */
#define PP 76
__global__ __launch_bounds__(256) void attn_kernel(
    const unsigned short* __restrict__ Qbf, const unsigned short* __restrict__ Kbf,
    const unsigned short* __restrict__ Vbf, unsigned short* __restrict__ ctxbf)
{
  const int q0 = blockIdx.x * 128;
  const int h  = blockIdx.y;
  const int b  = blockIdx.z;
  const int tid = threadIdx.x, lane = tid & 63, w = tid >> 6;
  const int c = lane & 15, g = lane >> 4;
  const int w0 = q0 - WWIN;               // staged window global start

  __shared__ unsigned short K_l[160*KP];
  __shared__ unsigned short V_l[160*KP];
  __shared__ unsigned short P_l[4][32*PP];

  const long baseRow = (long)b*SS*DD + (long)h*DKK;
  const int qw0   = q0 + w*32;            // wave's first query
  const int kbase = w*32;                 // wave's key window start (staged row)

  // Q fragment loads issued FIRST: global latency overlaps LDS staging below
  bf16x8 aq[2][2];
  for (int m = 0; m < 2; ++m)
    for (int kk = 0; kk < 2; ++kk)
      aq[m][kk] = *reinterpret_cast<const bf16x8*>(
          Qbf + baseRow + (long)(qw0 + m*16 + c)*DD + kk*32 + g*8);

  // stage K/V rows [w0, w0+160), zero-fill out-of-sequence rows
  for (int i = 0; i < 5; ++i) {
    int u = i*256 + tid;                  // 1280 chunks of 8 elems
    int row = u >> 3, c8 = (u & 7) * 8;
    int gk = w0 + row;
    u32x4 kv = {0,0,0,0}, vv = {0,0,0,0};
    if (gk >= 0 && gk < SS) {
      kv = *(const u32x4*)(Kbf + baseRow + (long)gk*DD + c8);
      vv = *(const u32x4*)(Vbf + baseRow + (long)gk*DD + c8);
    }
    *(u32x4*)(&K_l[row*KP + c8]) = kv;
    *(u32x4*)(&V_l[row*KP + c8]) = vv;
  }
  __syncthreads();

  // ---- QK^T ----
  f32x4 accs[2][4] = {};
  __builtin_amdgcn_s_setprio(1);
  for (int kk = 0; kk < 2; ++kk) {
    bf16x8 bk[4];
    for (int n = 0; n < 4; ++n)
      bk[n] = *reinterpret_cast<const bf16x8*>(&K_l[(kbase + n*16 + c)*KP + kk*32 + g*8]);
    for (int m = 0; m < 2; ++m)
      for (int n = 0; n < 4; ++n)
        accs[m][n] = __builtin_amdgcn_mfma_f32_16x16x32_bf16(aq[m][kk], bk[n], accs[m][n], 0, 0, 0);
  }
  __builtin_amdgcn_s_setprio(0);

  // ---- band mask + row softmax (rows live in 16-lane xor groups) ----
  float pden[2][4];
  for (int m = 0; m < 2; ++m) {
    for (int r = 0; r < 4; ++r) {
      int qi = m*16 + g*4 + r;            // 0..31
      float sv[4];
      float mx = -INFINITY;
      for (int n = 0; n < 4; ++n) {
        int kr = n*16 + c;                // 0..63
        int d  = kr - qi;
        int kg = w0 + kbase + kr;         // global key index
        bool ok = (d >= 0) && (d <= 2*WWIN) && (kg >= 0) && (kg < SS);
        sv[n] = ok ? accs[m][n][r] * 0.125f : -INFINITY;
        mx = fmaxf(mx, sv[n]);
      }
      for (int off = 1; off < 16; off <<= 1) mx = fmaxf(mx, __shfl_xor(mx, off, 64));
      float sum = 0.f;
      for (int n = 0; n < 4; ++n) {
        float e = __expf(sv[n] - mx);     // exp(-inf)=0 on masked
        sum += e;
        P_l[w][(m*16 + g*4 + r)*PP + n*16 + c] = f2bf(e);
      }
      for (int off = 1; off < 16; off <<= 1) sum += __shfl_xor(sum, off, 64);
      pden[m][r] = sum;
    }
  }
  __syncthreads();

  // ---- PV: A = P (LDS), B = V (LDS, strided scalar gather) ----
  f32x4 acco[2][4] = {};
  for (int kk = 0; kk < 2; ++kk) {
    bf16x8 pa[2];
    for (int m = 0; m < 2; ++m)
      pa[m] = *reinterpret_cast<const bf16x8*>(&P_l[w][(m*16 + c)*PP + kk*32 + g*8]);
    bf16x8 bv[4];
    int kb = kbase + kk*32 + g*8;
    for (int n = 0; n < 4; ++n) {
      bfu8 t;
      for (int j = 0; j < 8; ++j) t[j] = V_l[(kb + j)*KP + n*16 + c];
      bv[n] = *reinterpret_cast<bf16x8*>(&t);
    }
    __builtin_amdgcn_s_setprio(1);
    for (int m = 0; m < 2; ++m)
      for (int n = 0; n < 4; ++n)
        acco[m][n] = __builtin_amdgcn_mfma_f32_16x16x32_bf16(pa[m], bv[n], acco[m][n], 0, 0, 0);
    __builtin_amdgcn_s_setprio(0);
  }

  // ---- normalize + write ctx (bf16) ----
  for (int m = 0; m < 2; ++m) {
    for (int r = 0; r < 4; ++r) {
      int q = qw0 + m*16 + g*4 + r;
      float inv = 1.f / pden[m][r];
      for (int n = 0; n < 4; ++n)
        ctxbf[baseRow + (long)q*DD + n*16 + c] = f2bf(acco[m][n][r] * inv);
    }
  }
}

extern "C" void kernel_launch(void* const* d_in, const int* in_sizes, int n_in,
                              void* d_out, int out_size, void* d_ws, size_t ws_size,
                              hipStream_t stream) {
  const float* q  = (const float*)d_in[0];
  const float* k  = (const float*)d_in[1];
  const float* v  = (const float*)d_in[2];
  const float* Wq = (const float*)d_in[3];
  const float* bq = (const float*)d_in[4];
  const float* Wk = (const float*)d_in[5];
  const float* bk = (const float*)d_in[6];
  const float* Wv = (const float*)d_in[7];
  const float* bv = (const float*)d_in[8];
  const float* Wo = (const float*)d_in[9];
  const float* bo = (const float*)d_in[10];

  char* ws = (char*)d_ws;
  unsigned short* wtbf     = (unsigned short*)(ws);              // 4*NKE bf16 = 2,097,152 B
  float*          bias_all = (float*)(ws + 2097152);             // 6,144 B
  unsigned short* qkvbf    = (unsigned short*)(ws + 2103296);    // 3*MKE bf16 = 25,165,824 B
  unsigned short* ctxbf    = (unsigned short*)(ws + 27269120);   // MKE bf16   =  8,388,608 B

  convert_w<<<262, 256, 0, stream>>>(Wq, Wk, Wv, Wo, bq, bk, bv, wtbf, bias_all);
  gemm_rowpanel<1,1><<<dim3(MTOT/32, 1, 3), 256, 0, stream>>>(
      q, k, v, wtbf, NKE, bias_all, DD,
      (void*)qkvbf, MKE, DD, DD);
  attn_kernel<<<dim3(SS/128, HH, BB), 256, 0, stream>>>(
      qkvbf, qkvbf + MKE, qkvbf + 2*MKE, ctxbf);
  gemm_rowpanel<0,0><<<dim3(MTOT/32, 1, 1), 256, 0, stream>>>(
      ctxbf, ctxbf, ctxbf, wtbf + 3*NKE, 0, bo, 0,
      (void*)d_out, 0, DD, DD);
}

// Round 6
// 158.421 us; speedup vs baseline: 1.0657x; 1.0657x over previous
//
#include <hip/hip_runtime.h>

typedef __attribute__((ext_vector_type(8))) short bf16x8;
typedef __attribute__((ext_vector_type(4))) float f32x4;
typedef __attribute__((ext_vector_type(4))) unsigned int u32x4;
typedef __attribute__((ext_vector_type(8))) unsigned short bfu8;

#define BB 4
#define SS 2048
#define DD 512
#define HH 8
#define DKK 64
#define WWIN 16
#define MTOT (BB*SS)                 /* 8192 */
#define MKE  ((long)MTOT*DD)         /* 4,194,304 elems */
#define NKE  ((long)DD*DD)           /* 262,144 elems */

__device__ __forceinline__ unsigned short f2bf(float f) {
  unsigned int u = __float_as_uint(f);
  u += 0x7fffu + ((u >> 16) & 1u);
  return (unsigned short)(u >> 16);
}
__device__ __forceinline__ float bf2f(unsigned short s) {
  return __uint_as_float(((unsigned int)s) << 16);
}

__device__ __forceinline__ void gload_lds16(const unsigned short* g, unsigned short* l) {
  __builtin_amdgcn_global_load_lds((const __attribute__((address_space(1))) void*)g,
                                   (__attribute__((address_space(3))) void*)l, 16, 0, 0);
}

// -------- transpose+convert weights: Wt[n][k] = bf16(W[k][n]); blocks 256..261 gather biases --------
__global__ __launch_bounds__(256) void convert_w(
    const float* __restrict__ Wq, const float* __restrict__ Wk,
    const float* __restrict__ Wv, const float* __restrict__ Wo,
    const float* __restrict__ bq, const float* __restrict__ bk, const float* __restrict__ bv,
    unsigned short* __restrict__ wt, float* __restrict__ bias_all)
{
  int bx = blockIdx.x;
  if (bx >= 256) {                       // bias gather: 6 blocks x 256 = 1536
    int idx = (bx - 256) * 256 + threadIdx.x;
    bias_all[idx] = idx < DD ? bq[idx] : (idx < 2*DD ? bk[idx-DD] : bv[idx-2*DD]);
    return;
  }
  int wm = bx >> 6;
  int tile = bx & 63;
  int tr = tile >> 3, tc = tile & 7;     // 8x8 tiles of 64x64
  const float* src = wm==0 ? Wq : wm==1 ? Wk : wm==2 ? Wv : Wo;
  unsigned short* dst = wt + (long)wm*NKE;
  __shared__ float tl[64][65];
  int t = threadIdx.x;
  int cr = t >> 6;                       // 0..3
  int cc = t & 63;
  for (int p = 0; p < 16; ++p) {
    int row = p*4 + cr;
    tl[row][cc] = src[(long)(tr*64+row)*DD + tc*64 + cc];
  }
  __syncthreads();
  for (int p = 0; p < 16; ++p) {
    int orow = p*4 + cr;                 // output row = original col
    dst[(long)(tc*64 + orow)*DD + tr*64 + cc] = f2bf(tl[cc][orow]);
  }
}

// -------- double-buffered 128x128 MFMA GEMM, XOR-swizzled LDS, XCD-grouped grid --------
// C[M,N] = A[M,K] @ Bt[N,K]^T + bias. BK=64, 4 waves (2x2), 4x4 16x16x32 frags/wave.
// LDS swizzle: 16B slot s of row r stored at slot s^(r&7) -> conflict-free ds_read_b128.
// B staged by global_load_lds with inverse-swizzled SOURCE (linear dest, rule both-sides).
// A_FP32: A reg-staged fp32->bf16 with swizzled ds_write. Pipeline: stage(t+1) before
// compute(t), one barrier/iter -> loads in flight under MFMA.
// 1D grid: bid -> xcd=bid&7; 4 consecutive slots on one XCD = 4 n-tiles of one (z,m) panel.
template<int OUT_BF16, int A_FP32>
__global__ __launch_bounds__(256, 2) void gemm_dbuf(
    const void* __restrict__ a0, const void* __restrict__ a1, const void* __restrict__ a2,
    const unsigned short* __restrict__ Btbase, long bZ,
    const float* __restrict__ biasBase, long biasZ,
    void* __restrict__ outBase, long outZ, int N, int K)
{
  const int bid   = blockIdx.x;
  const int slot  = bid >> 3;
  const int panel = (bid & 7) + 8 * (slot >> 2);   // (z,m) panel, same XCD for its 4 n-blocks
  const int n0 = (slot & 3) * 128;
  const int z  = panel >> 6;
  const int m0 = (panel & 63) * 128;

  const void* Av = z==0 ? a0 : z==1 ? a1 : a2;
  const unsigned short* Bt = Btbase + (long)z*bZ;
  const float* bias = biasBase + (long)z*biasZ;

  const int tid = threadIdx.x, lane = tid & 63, w = tid >> 6;
  const int wr = w >> 1, wc = w & 1;
  const int c = lane & 15, g = lane >> 4;

  __shared__ unsigned short lA[2][128*64];
  __shared__ unsigned short lB[2][128*64];

  f32x4 acc[4][4] = {};
  float4 fa[8];
  const int NT = K >> 6;

  auto stageB = [&](int buf, int kt) {
    #pragma unroll
    for (int j = 0; j < 4; ++j) {
      int u = w*256 + j*64 + lane;                  // 16B chunk id 0..1023
      int row = u >> 3, sl = (u & 7) ^ (row & 7);   // inverse-swizzled source slot
      gload_lds16(Bt + (long)(n0 + row)*K + kt + sl*8, &lB[buf][(w*256 + j*64)*8]);
    }
  };
  auto stageA_lds = [&](int buf, int kt) {
    const unsigned short* Ab = (const unsigned short*)Av;
    #pragma unroll
    for (int j = 0; j < 4; ++j) {
      int u = w*256 + j*64 + lane;
      int row = u >> 3, sl = (u & 7) ^ (row & 7);
      gload_lds16(Ab + (long)(m0 + row)*K + kt + sl*8, &lA[buf][(w*256 + j*64)*8]);
    }
  };
  auto loadA = [&](int kt) {
    const float* Af = (const float*)Av;
    #pragma unroll
    for (int i = 0; i < 4; ++i) {
      int u = i*256 + tid;
      int row = u >> 3, col = (u & 7) * 8;
      const float* s = Af + (long)(m0 + row)*K + kt + col;
      fa[2*i]   = *(const float4*)s;
      fa[2*i+1] = *(const float4*)(s + 4);
    }
  };
  auto writeA = [&](int buf) {
    #pragma unroll
    for (int i = 0; i < 4; ++i) {
      int u = i*256 + tid;
      int row = u >> 3, sl = u & 7;
      bfu8 o;
      o[0]=f2bf(fa[2*i].x);   o[1]=f2bf(fa[2*i].y);   o[2]=f2bf(fa[2*i].z);   o[3]=f2bf(fa[2*i].w);
      o[4]=f2bf(fa[2*i+1].x); o[5]=f2bf(fa[2*i+1].y); o[6]=f2bf(fa[2*i+1].z); o[7]=f2bf(fa[2*i+1].w);
      *(bfu8*)&lA[buf][row*64 + (sl ^ (row & 7))*8] = o;
    }
  };
  auto compute = [&](int buf) {
    #pragma unroll
    for (int kk = 0; kk < 2; ++kk) {
      bf16x8 af[4], bfr[4];
      #pragma unroll
      for (int m = 0; m < 4; ++m) {
        int row = wr*64 + m*16 + c;
        af[m] = *reinterpret_cast<const bf16x8*>(&lA[buf][row*64 + (((kk<<2)+g) ^ (row & 7))*8]);
      }
      #pragma unroll
      for (int nn = 0; nn < 4; ++nn) {
        int col = wc*64 + nn*16 + c;
        bfr[nn] = *reinterpret_cast<const bf16x8*>(&lB[buf][col*64 + (((kk<<2)+g) ^ (col & 7))*8]);
      }
      __builtin_amdgcn_s_setprio(1);
      #pragma unroll
      for (int m = 0; m < 4; ++m)
        #pragma unroll
        for (int nn = 0; nn < 4; ++nn)
          acc[m][nn] = __builtin_amdgcn_mfma_f32_16x16x32_bf16(af[m], bfr[nn], acc[m][nn], 0, 0, 0);
      __builtin_amdgcn_s_setprio(0);
    }
  };

  // prologue: fill buffer 0
  if (A_FP32) loadA(0); else stageA_lds(0, 0);
  stageB(0, 0);
  if (A_FP32) writeA(0);
  __syncthreads();

  int cur = 0;
  for (int t = 0; t < NT; ++t) {
    int nxt = cur ^ 1;
    if (t + 1 < NT) {                       // issue next-tile loads BEFORE compute
      if (A_FP32) loadA((t+1) << 6); else stageA_lds(nxt, (t+1) << 6);
      stageB(nxt, (t+1) << 6);
    }
    compute(cur);
    if (A_FP32 && t + 1 < NT) writeA(nxt);  // vmcnt wait lands here, hidden by MFMA
    __syncthreads();                        // drains vmcnt+lgkm: next buffer ready
    cur = nxt;
  }

  // epilogue: C/D layout col=lane&15, row=(lane>>4)*4+reg
  #pragma unroll
  for (int m = 0; m < 4; ++m) {
    int rbase = m0 + wr*64 + m*16 + g*4;
    #pragma unroll
    for (int nn = 0; nn < 4; ++nn) {
      int col = n0 + wc*64 + nn*16 + c;
      float bv = bias[col];
      #pragma unroll
      for (int r = 0; r < 4; ++r) {
        float val = acc[m][nn][r] + bv;
        long idx = (long)z*outZ + (long)(rbase + r)*N + col;
        if (OUT_BF16) ((unsigned short*)outBase)[idx] = f2bf(val);
        else          ((float*)outBase)[idx] = val;
      }
    }
  }
}

// ---------------- banded local attention via MFMA ----------------
// grid: (S/128, H, B); block 256 = 4 waves; wave w owns queries [q0+32w, q0+32w+32)
// K/V window staged: rows [q0-16, q0+144) = 160 rows x 64 dk (zero-filled OOB)
#define KP 76   /* LDS row pad (elems): keeps hot ds_read <=2-way bank aliased */
#define PP 76
__global__ __launch_bounds__(256) void attn_kernel(
    const unsigned short* __restrict__ Qbf, const unsigned short* __restrict__ Kbf,
    const unsigned short* __restrict__ Vbf, unsigned short* __restrict__ ctxbf)
{
  const int q0 = blockIdx.x * 128;
  const int h  = blockIdx.y;
  const int b  = blockIdx.z;
  const int tid = threadIdx.x, lane = tid & 63, w = tid >> 6;
  const int c = lane & 15, g = lane >> 4;
  const int w0 = q0 - WWIN;               // staged window global start

  __shared__ unsigned short K_l[160*KP];
  __shared__ unsigned short V_l[160*KP];
  __shared__ unsigned short P_l[4][32*PP];

  const long baseRow = (long)b*SS*DD + (long)h*DKK;
  const int qw0   = q0 + w*32;            // wave's first query
  const int kbase = w*32;                 // wave's key window start (staged row)

  // Q fragment loads issued FIRST: global latency overlaps LDS staging below
  bf16x8 aq[2][2];
  for (int m = 0; m < 2; ++m)
    for (int kk = 0; kk < 2; ++kk)
      aq[m][kk] = *reinterpret_cast<const bf16x8*>(
          Qbf + baseRow + (long)(qw0 + m*16 + c)*DD + kk*32 + g*8);

  // stage K/V rows [w0, w0+160), zero-fill out-of-sequence rows
  for (int i = 0; i < 5; ++i) {
    int u = i*256 + tid;                  // 1280 chunks of 8 elems
    int row = u >> 3, c8 = (u & 7) * 8;
    int gk = w0 + row;
    u32x4 kv = {0,0,0,0}, vv = {0,0,0,0};
    if (gk >= 0 && gk < SS) {
      kv = *(const u32x4*)(Kbf + baseRow + (long)gk*DD + c8);
      vv = *(const u32x4*)(Vbf + baseRow + (long)gk*DD + c8);
    }
    *(u32x4*)(&K_l[row*KP + c8]) = kv;
    *(u32x4*)(&V_l[row*KP + c8]) = vv;
  }
  __syncthreads();

  // ---- QK^T ----
  f32x4 accs[2][4] = {};
  __builtin_amdgcn_s_setprio(1);
  for (int kk = 0; kk < 2; ++kk) {
    bf16x8 bk[4];
    for (int n = 0; n < 4; ++n)
      bk[n] = *reinterpret_cast<const bf16x8*>(&K_l[(kbase + n*16 + c)*KP + kk*32 + g*8]);
    for (int m = 0; m < 2; ++m)
      for (int n = 0; n < 4; ++n)
        accs[m][n] = __builtin_amdgcn_mfma_f32_16x16x32_bf16(aq[m][kk], bk[n], accs[m][n], 0, 0, 0);
  }
  __builtin_amdgcn_s_setprio(0);

  // ---- band mask + row softmax (rows live in 16-lane xor groups) ----
  float pden[2][4];
  for (int m = 0; m < 2; ++m) {
    for (int r = 0; r < 4; ++r) {
      int qi = m*16 + g*4 + r;            // 0..31
      float sv[4];
      float mx = -INFINITY;
      for (int n = 0; n < 4; ++n) {
        int kr = n*16 + c;                // 0..63
        int d  = kr - qi;
        int kg = w0 + kbase + kr;         // global key index
        bool ok = (d >= 0) && (d <= 2*WWIN) && (kg >= 0) && (kg < SS);
        sv[n] = ok ? accs[m][n][r] * 0.125f : -INFINITY;
        mx = fmaxf(mx, sv[n]);
      }
      for (int off = 1; off < 16; off <<= 1) mx = fmaxf(mx, __shfl_xor(mx, off, 64));
      float sum = 0.f;
      for (int n = 0; n < 4; ++n) {
        float e = __expf(sv[n] - mx);     // exp(-inf)=0 on masked
        sum += e;
        P_l[w][(m*16 + g*4 + r)*PP + n*16 + c] = f2bf(e);
      }
      for (int off = 1; off < 16; off <<= 1) sum += __shfl_xor(sum, off, 64);
      pden[m][r] = sum;
    }
  }
  __syncthreads();

  // ---- PV: A = P (LDS), B = V (LDS, strided scalar gather) ----
  f32x4 acco[2][4] = {};
  for (int kk = 0; kk < 2; ++kk) {
    bf16x8 pa[2];
    for (int m = 0; m < 2; ++m)
      pa[m] = *reinterpret_cast<const bf16x8*>(&P_l[w][(m*16 + c)*PP + kk*32 + g*8]);
    bf16x8 bv[4];
    int kb = kbase + kk*32 + g*8;
    for (int n = 0; n < 4; ++n) {
      bfu8 t;
      for (int j = 0; j < 8; ++j) t[j] = V_l[(kb + j)*KP + n*16 + c];
      bv[n] = *reinterpret_cast<bf16x8*>(&t);
    }
    __builtin_amdgcn_s_setprio(1);
    for (int m = 0; m < 2; ++m)
      for (int n = 0; n < 4; ++n)
        acco[m][n] = __builtin_amdgcn_mfma_f32_16x16x32_bf16(pa[m], bv[n], acco[m][n], 0, 0, 0);
    __builtin_amdgcn_s_setprio(0);
  }

  // ---- normalize + write ctx (bf16) ----
  for (int m = 0; m < 2; ++m) {
    for (int r = 0; r < 4; ++r) {
      int q = qw0 + m*16 + g*4 + r;
      float inv = 1.f / pden[m][r];
      for (int n = 0; n < 4; ++n)
        ctxbf[baseRow + (long)q*DD + n*16 + c] = f2bf(acco[m][n][r] * inv);
    }
  }
}

extern "C" void kernel_launch(void* const* d_in, const int* in_sizes, int n_in,
                              void* d_out, int out_size, void* d_ws, size_t ws_size,
                              hipStream_t stream) {
  const float* q  = (const float*)d_in[0];
  const float* k  = (const float*)d_in[1];
  const float* v  = (const float*)d_in[2];
  const float* Wq = (const float*)d_in[3];
  const float* bq = (const float*)d_in[4];
  const float* Wk = (const float*)d_in[5];
  const float* bk = (const float*)d_in[6];
  const float* Wv = (const float*)d_in[7];
  const float* bv = (const float*)d_in[8];
  const float* Wo = (const float*)d_in[9];
  const float* bo = (const float*)d_in[10];

  char* ws = (char*)d_ws;
  unsigned short* wtbf     = (unsigned short*)(ws);              // 4*NKE bf16 = 2,097,152 B
  float*          bias_all = (float*)(ws + 2097152);             // 6,144 B
  unsigned short* qkvbf    = (unsigned short*)(ws + 2103296);    // 3*MKE bf16 = 25,165,824 B
  unsigned short* ctxbf    = (unsigned short*)(ws + 27269120);   // MKE bf16   =  8,388,608 B

  convert_w<<<262, 256, 0, stream>>>(Wq, Wk, Wv, Wo, bq, bk, bv, wtbf, bias_all);
  gemm_dbuf<1,1><<<768, 256, 0, stream>>>(
      q, k, v, wtbf, NKE, bias_all, DD,
      (void*)qkvbf, MKE, DD, DD);
  attn_kernel<<<dim3(SS/128, HH, BB), 256, 0, stream>>>(
      qkvbf, qkvbf + MKE, qkvbf + 2*MKE, ctxbf);
  gemm_dbuf<0,0><<<256, 256, 0, stream>>>(
      ctxbf, ctxbf, ctxbf, wtbf + 3*NKE, 0, bo, 0,
      (void*)d_out, 0, DD, DD);
}

// Round 7
// 156.573 us; speedup vs baseline: 1.0783x; 1.0118x over previous
//
#include <hip/hip_runtime.h>

typedef __attribute__((ext_vector_type(8))) short bf16x8;
typedef __attribute__((ext_vector_type(4))) float f32x4;
typedef __attribute__((ext_vector_type(4))) unsigned int u32x4;
typedef __attribute__((ext_vector_type(8))) unsigned short bfu8;

#define BB 4
#define SS 2048
#define DD 512
#define HH 8
#define DKK 64
#define WWIN 16
#define MTOT (BB*SS)                 /* 8192 */
#define MKE  ((long)MTOT*DD)         /* 4,194,304 elems */
#define NKE  ((long)DD*DD)           /* 262,144 elems */

__device__ __forceinline__ unsigned short f2bf(float f) {
  unsigned int u = __float_as_uint(f);
  u += 0x7fffu + ((u >> 16) & 1u);
  return (unsigned short)(u >> 16);
}
__device__ __forceinline__ float bf2f(unsigned short s) {
  return __uint_as_float(((unsigned int)s) << 16);
}

// raw barrier discipline: no vmcnt(0) drain in the K-loop (rule #18 fencing)
#define SBAR() do { __builtin_amdgcn_sched_barrier(0); __builtin_amdgcn_s_barrier(); \
                    __builtin_amdgcn_sched_barrier(0); } while (0)
#define LGKM0() do { asm volatile("s_waitcnt lgkmcnt(0)" ::: "memory"); \
                     __builtin_amdgcn_sched_barrier(0); } while (0)

// -------- transpose+convert weights: Wt[n][k] = bf16(W[k][n]); blocks 256..261 gather biases --------
__global__ __launch_bounds__(256) void convert_w(
    const float* __restrict__ Wq, const float* __restrict__ Wk,
    const float* __restrict__ Wv, const float* __restrict__ Wo,
    const float* __restrict__ bq, const float* __restrict__ bk, const float* __restrict__ bv,
    unsigned short* __restrict__ wt, float* __restrict__ bias_all)
{
  int bx = blockIdx.x;
  if (bx >= 256) {                       // bias gather: 6 blocks x 256 = 1536
    int idx = (bx - 256) * 256 + threadIdx.x;
    bias_all[idx] = idx < DD ? bq[idx] : (idx < 2*DD ? bk[idx-DD] : bv[idx-2*DD]);
    return;
  }
  int wm = bx >> 6;
  int tile = bx & 63;
  int tr = tile >> 3, tc = tile & 7;     // 8x8 tiles of 64x64
  const float* src = wm==0 ? Wq : wm==1 ? Wk : wm==2 ? Wv : Wo;
  unsigned short* dst = wt + (long)wm*NKE;
  __shared__ float tl[64][65];
  int t = threadIdx.x;
  int cr = t >> 6;                       // 0..3
  int cc = t & 63;
  for (int p = 0; p < 16; ++p) {
    int row = p*4 + cr;
    tl[row][cc] = src[(long)(tr*64+row)*DD + tc*64 + cc];
  }
  __syncthreads();
  for (int p = 0; p < 16; ++p) {
    int orow = p*4 + cr;                 // output row = original col
    dst[(long)(tc*64 + orow)*DD + tr*64 + cc] = f2bf(tl[cc][orow]);
  }
}

// -------- pipelined 128x128 MFMA GEMM, single LDS buffer + register prefetch (T14) --------
// C[M,N] = A[M,K] @ Bt[N,K]^T + bias. BK=64, 4 waves (2x2), 4x4 16x16x32 frags/wave.
// Per iter: issue t+1 global loads to regs -> compute(t) from LDS -> naked s_barrier
// (readers done; NO vmcnt drain) -> reg->LDS write (counted vmcnt waits land here,
// after loads had the whole compute to fly) -> lgkmcnt(0)+barrier. 32 KB LDS ->
// 3 blocks/CU (launch_bounds(256,3)) for latency-hiding TLP.
// LDS swizzle: 16B slot s of row r at slot s^(r&7) -> conflict-free ds_read_b128.
template<int OUT_BF16, int A_FP32>
__global__ __launch_bounds__(256, 3) void gemm_pipe(
    const void* __restrict__ a0, const void* __restrict__ a1, const void* __restrict__ a2,
    const unsigned short* __restrict__ Btbase, long bZ,
    const float* __restrict__ biasBase, long biasZ,
    void* __restrict__ outBase, long outZ, int N, int K)
{
  const int bid   = blockIdx.x;
  const int slot  = bid >> 3;
  const int panel = (bid & 7) + 8 * (slot >> 2);   // (z,m) panel; its 4 n-blocks share an XCD
  const int n0 = (slot & 3) * 128;
  const int z  = panel >> 6;
  const int m0 = (panel & 63) * 128;

  const void* Av = z==0 ? a0 : z==1 ? a1 : a2;
  const unsigned short* Bt = Btbase + (long)z*bZ;
  const float* bias = biasBase + (long)z*biasZ;

  const int tid = threadIdx.x, lane = tid & 63, w = tid >> 6;
  const int wr = w >> 1, wc = w & 1;
  const int c = lane & 15, g = lane >> 4;

  __shared__ unsigned short lA[128*64];
  __shared__ unsigned short lB[128*64];

  f32x4 acc[4][4] = {};
  float4 fa32[8];      // A fp32 prefetch (A_FP32)
  bfu8   fa16[4];      // A bf16 prefetch (!A_FP32)
  bfu8   fb[4];        // B prefetch
  const int NT = K >> 6;

  auto loadA = [&](int kt) {
    if (A_FP32) {
      const float* Af = (const float*)Av;
      #pragma unroll
      for (int i = 0; i < 4; ++i) {
        int u = i*256 + tid, row = u >> 3, col = (u & 7) * 8;
        const float* s = Af + (long)(m0 + row)*K + kt + col;
        fa32[2*i]   = *(const float4*)s;
        fa32[2*i+1] = *(const float4*)(s + 4);
      }
    } else {
      const unsigned short* Ab = (const unsigned short*)Av;
      #pragma unroll
      for (int i = 0; i < 4; ++i) {
        int u = i*256 + tid, row = u >> 3, col = (u & 7) * 8;
        fa16[i] = *(const bfu8*)(Ab + (long)(m0 + row)*K + kt + col);
      }
    }
  };
  auto loadB = [&](int kt) {
    #pragma unroll
    for (int i = 0; i < 4; ++i) {
      int u = i*256 + tid, row = u >> 3, col = (u & 7) * 8;
      fb[i] = *(const bfu8*)(Bt + (long)(n0 + row)*K + kt + col);
    }
  };
  auto writeA = [&]() {
    #pragma unroll
    for (int i = 0; i < 4; ++i) {
      int u = i*256 + tid, row = u >> 3, sl = u & 7;
      bfu8 o;
      if (A_FP32) {
        o[0]=f2bf(fa32[2*i].x);   o[1]=f2bf(fa32[2*i].y);
        o[2]=f2bf(fa32[2*i].z);   o[3]=f2bf(fa32[2*i].w);
        o[4]=f2bf(fa32[2*i+1].x); o[5]=f2bf(fa32[2*i+1].y);
        o[6]=f2bf(fa32[2*i+1].z); o[7]=f2bf(fa32[2*i+1].w);
      } else o = fa16[i];
      *(bfu8*)&lA[row*64 + (sl ^ (row & 7))*8] = o;
    }
  };
  auto writeB = [&]() {
    #pragma unroll
    for (int i = 0; i < 4; ++i) {
      int u = i*256 + tid, row = u >> 3, sl = u & 7;
      *(bfu8*)&lB[row*64 + (sl ^ (row & 7))*8] = fb[i];
    }
  };
  auto compute = [&]() {
    #pragma unroll
    for (int kk = 0; kk < 2; ++kk) {
      bf16x8 af[4], bfr[4];
      #pragma unroll
      for (int m = 0; m < 4; ++m) {
        int row = wr*64 + m*16 + c;
        af[m] = *reinterpret_cast<const bf16x8*>(&lA[row*64 + (((kk<<2)+g) ^ (row & 7))*8]);
      }
      #pragma unroll
      for (int nn = 0; nn < 4; ++nn) {
        int col = wc*64 + nn*16 + c;
        bfr[nn] = *reinterpret_cast<const bf16x8*>(&lB[col*64 + (((kk<<2)+g) ^ (col & 7))*8]);
      }
      __builtin_amdgcn_s_setprio(1);
      #pragma unroll
      for (int m = 0; m < 4; ++m)
        #pragma unroll
        for (int nn = 0; nn < 4; ++nn)
          acc[m][nn] = __builtin_amdgcn_mfma_f32_16x16x32_bf16(af[m], bfr[nn], acc[m][nn], 0, 0, 0);
      __builtin_amdgcn_s_setprio(0);
    }
  };

  // prologue: fill LDS for tile 0 (one exposed latency)
  loadA(0); loadB(0);
  writeA(); writeB();
  LGKM0(); SBAR();

  for (int t = 0; t < NT; ++t) {
    if (t + 1 < NT) { loadA((t+1) << 6); loadB((t+1) << 6); }  // in flight across compute
    compute();
    if (t + 1 < NT) {
      SBAR();                    // readers done; naked barrier, no vmcnt drain
      writeA(); writeB();        // counted vmcnt waits land here
      LGKM0(); SBAR();           // writes visible to all waves
    }
  }

  // epilogue: C/D layout col=lane&15, row=(lane>>4)*4+reg
  #pragma unroll
  for (int m = 0; m < 4; ++m) {
    int rbase = m0 + wr*64 + m*16 + g*4;
    #pragma unroll
    for (int nn = 0; nn < 4; ++nn) {
      int col = n0 + wc*64 + nn*16 + c;
      float bv = bias[col];
      #pragma unroll
      for (int r = 0; r < 4; ++r) {
        float val = acc[m][nn][r] + bv;
        long idx = (long)z*outZ + (long)(rbase + r)*N + col;
        if (OUT_BF16) ((unsigned short*)outBase)[idx] = f2bf(val);
        else          ((float*)outBase)[idx] = val;
      }
    }
  }
}

// ---------------- banded local attention via MFMA ----------------
// grid: (S/128, H, B); block 256 = 4 waves; wave w owns queries [q0+32w, q0+32w+32)
// K/V window staged: rows [q0-16, q0+144) = 160 rows x 64 dk (zero-filled OOB)
#define KP 76   /* LDS row pad (elems): keeps hot ds_read <=2-way bank aliased */
#define PP 76
__global__ __launch_bounds__(256) void attn_kernel(
    const unsigned short* __restrict__ Qbf, const unsigned short* __restrict__ Kbf,
    const unsigned short* __restrict__ Vbf, unsigned short* __restrict__ ctxbf)
{
  const int q0 = blockIdx.x * 128;
  const int h  = blockIdx.y;
  const int b  = blockIdx.z;
  const int tid = threadIdx.x, lane = tid & 63, w = tid >> 6;
  const int c = lane & 15, g = lane >> 4;
  const int w0 = q0 - WWIN;               // staged window global start

  __shared__ unsigned short K_l[160*KP];
  __shared__ unsigned short V_l[160*KP];
  __shared__ unsigned short P_l[4][32*PP];

  const long baseRow = (long)b*SS*DD + (long)h*DKK;
  const int qw0   = q0 + w*32;            // wave's first query
  const int kbase = w*32;                 // wave's key window start (staged row)

  // Q fragment loads issued FIRST: global latency overlaps LDS staging below
  bf16x8 aq[2][2];
  for (int m = 0; m < 2; ++m)
    for (int kk = 0; kk < 2; ++kk)
      aq[m][kk] = *reinterpret_cast<const bf16x8*>(
          Qbf + baseRow + (long)(qw0 + m*16 + c)*DD + kk*32 + g*8);

  // stage K/V rows [w0, w0+160), zero-fill out-of-sequence rows
  for (int i = 0; i < 5; ++i) {
    int u = i*256 + tid;                  // 1280 chunks of 8 elems
    int row = u >> 3, c8 = (u & 7) * 8;
    int gk = w0 + row;
    u32x4 kv = {0,0,0,0}, vv = {0,0,0,0};
    if (gk >= 0 && gk < SS) {
      kv = *(const u32x4*)(Kbf + baseRow + (long)gk*DD + c8);
      vv = *(const u32x4*)(Vbf + baseRow + (long)gk*DD + c8);
    }
    *(u32x4*)(&K_l[row*KP + c8]) = kv;
    *(u32x4*)(&V_l[row*KP + c8]) = vv;
  }
  __syncthreads();

  // ---- QK^T ----
  f32x4 accs[2][4] = {};
  __builtin_amdgcn_s_setprio(1);
  for (int kk = 0; kk < 2; ++kk) {
    bf16x8 bk[4];
    for (int n = 0; n < 4; ++n)
      bk[n] = *reinterpret_cast<const bf16x8*>(&K_l[(kbase + n*16 + c)*KP + kk*32 + g*8]);
    for (int m = 0; m < 2; ++m)
      for (int n = 0; n < 4; ++n)
        accs[m][n] = __builtin_amdgcn_mfma_f32_16x16x32_bf16(aq[m][kk], bk[n], accs[m][n], 0, 0, 0);
  }
  __builtin_amdgcn_s_setprio(0);

  // ---- band mask + row softmax (rows live in 16-lane xor groups) ----
  float pden[2][4];
  for (int m = 0; m < 2; ++m) {
    for (int r = 0; r < 4; ++r) {
      int qi = m*16 + g*4 + r;            // 0..31
      float sv[4];
      float mx = -INFINITY;
      for (int n = 0; n < 4; ++n) {
        int kr = n*16 + c;                // 0..63
        int d  = kr - qi;
        int kg = w0 + kbase + kr;         // global key index
        bool ok = (d >= 0) && (d <= 2*WWIN) && (kg >= 0) && (kg < SS);
        sv[n] = ok ? accs[m][n][r] * 0.125f : -INFINITY;
        mx = fmaxf(mx, sv[n]);
      }
      for (int off = 1; off < 16; off <<= 1) mx = fmaxf(mx, __shfl_xor(mx, off, 64));
      float sum = 0.f;
      for (int n = 0; n < 4; ++n) {
        float e = __expf(sv[n] - mx);     // exp(-inf)=0 on masked
        sum += e;
        P_l[w][(m*16 + g*4 + r)*PP + n*16 + c] = f2bf(e);
      }
      for (int off = 1; off < 16; off <<= 1) sum += __shfl_xor(sum, off, 64);
      pden[m][r] = sum;
    }
  }
  __syncthreads();

  // ---- PV: A = P (LDS), B = V (LDS, strided scalar gather) ----
  f32x4 acco[2][4] = {};
  for (int kk = 0; kk < 2; ++kk) {
    bf16x8 pa[2];
    for (int m = 0; m < 2; ++m)
      pa[m] = *reinterpret_cast<const bf16x8*>(&P_l[w][(m*16 + c)*PP + kk*32 + g*8]);
    bf16x8 bv[4];
    int kb = kbase + kk*32 + g*8;
    for (int n = 0; n < 4; ++n) {
      bfu8 t;
      for (int j = 0; j < 8; ++j) t[j] = V_l[(kb + j)*KP + n*16 + c];
      bv[n] = *reinterpret_cast<bf16x8*>(&t);
    }
    __builtin_amdgcn_s_setprio(1);
    for (int m = 0; m < 2; ++m)
      for (int n = 0; n < 4; ++n)
        acco[m][n] = __builtin_amdgcn_mfma_f32_16x16x32_bf16(pa[m], bv[n], acco[m][n], 0, 0, 0);
    __builtin_amdgcn_s_setprio(0);
  }

  // ---- normalize + write ctx (bf16) ----
  for (int m = 0; m < 2; ++m) {
    for (int r = 0; r < 4; ++r) {
      int q = qw0 + m*16 + g*4 + r;
      float inv = 1.f / pden[m][r];
      for (int n = 0; n < 4; ++n)
        ctxbf[baseRow + (long)q*DD + n*16 + c] = f2bf(acco[m][n][r] * inv);
    }
  }
}

extern "C" void kernel_launch(void* const* d_in, const int* in_sizes, int n_in,
                              void* d_out, int out_size, void* d_ws, size_t ws_size,
                              hipStream_t stream) {
  const float* q  = (const float*)d_in[0];
  const float* k  = (const float*)d_in[1];
  const float* v  = (const float*)d_in[2];
  const float* Wq = (const float*)d_in[3];
  const float* bq = (const float*)d_in[4];
  const float* Wk = (const float*)d_in[5];
  const float* bk = (const float*)d_in[6];
  const float* Wv = (const float*)d_in[7];
  const float* bv = (const float*)d_in[8];
  const float* Wo = (const float*)d_in[9];
  const float* bo = (const float*)d_in[10];

  char* ws = (char*)d_ws;
  unsigned short* wtbf     = (unsigned short*)(ws);              // 4*NKE bf16 = 2,097,152 B
  float*          bias_all = (float*)(ws + 2097152);             // 6,144 B
  unsigned short* qkvbf    = (unsigned short*)(ws + 2103296);    // 3*MKE bf16 = 25,165,824 B
  unsigned short* ctxbf    = (unsigned short*)(ws + 27269120);   // MKE bf16   =  8,388,608 B

  convert_w<<<262, 256, 0, stream>>>(Wq, Wk, Wv, Wo, bq, bk, bv, wtbf, bias_all);
  gemm_pipe<1,1><<<768, 256, 0, stream>>>(
      q, k, v, wtbf, NKE, bias_all, DD,
      (void*)qkvbf, MKE, DD, DD);
  attn_kernel<<<dim3(SS/128, HH, BB), 256, 0, stream>>>(
      qkvbf, qkvbf + MKE, qkvbf + 2*MKE, ctxbf);
  gemm_pipe<0,0><<<256, 256, 0, stream>>>(
      ctxbf, ctxbf, ctxbf, wtbf + 3*NKE, 0, bo, 0,
      (void*)d_out, 0, DD, DD);
}